// Round 7
// baseline (475.857 us; speedup 1.0000x reference)
//
#include <hip/hip_runtime.h>
#include <math.h>

#define S_LEN 3072
#define DIM 1536
#define NHEADS 16
#define HDIM 96
#define NPAIR 48

typedef __attribute__((ext_vector_type(8))) _Float16 half8;
typedef __attribute__((ext_vector_type(4))) _Float16 half4v;
typedef __attribute__((ext_vector_type(2))) _Float16 half2v;
typedef __attribute__((ext_vector_type(4))) float f32x4;

__device__ inline void gload16(const void* g, void* l) {
    __builtin_amdgcn_global_load_lds(
        (const __attribute__((address_space(1))) void*)g,
        (__attribute__((address_space(3))) void*)l, 16, 0, 0);
}

__device__ inline unsigned int packh2(float a, float b) {
    _Float16 ha = (_Float16)a, hb = (_Float16)b;
    unsigned short ua = *(unsigned short*)&ha;
    unsigned short ub = *(unsigned short*)&hb;
    return (unsigned int)ua | ((unsigned int)ub << 16);
}

// ---------------- prep: fp32 -> fp16 elementwise ----------------
__global__ __launch_bounds__(256)
void convert_f32_f16(const float* __restrict__ src, _Float16* __restrict__ dst, int n4)
{
    int i = blockIdx.x * 256 + threadIdx.x;
    if (i < n4) {
        float4 v = *(const float4*)&src[(size_t)i * 4];
        half4v h = { (_Float16)v.x, (_Float16)v.y, (_Float16)v.z, (_Float16)v.w };
        *(half4v*)&dst[(size_t)i * 4] = h;
    }
}

// ---------------- prep: W[k][n] fp32 -> Wt[n][k] fp16 (64x64 LDS tiles) ----------------
__global__ __launch_bounds__(256)
void transpose_w(const float* __restrict__ w0, const float* __restrict__ w1,
                 const float* __restrict__ w2, const float* __restrict__ w3,
                 _Float16* __restrict__ wt)
{
    __shared__ _Float16 t[64][68];
    const int z = blockIdx.z;
    const float* W = (z == 0) ? w0 : (z == 1) ? w1 : (z == 2) ? w2 : w3;
    _Float16* O = wt + (size_t)z * DIM * DIM;
    const int k0 = blockIdx.y * 64, n0 = blockIdx.x * 64;
    const int tid = threadIdx.x;
    const int r = tid >> 4, c4 = (tid & 15) * 4;
#pragma unroll
    for (int g = 0; g < 4; g++) {
        int kk = r + g * 16;
        float4 v = *(const float4*)&W[(size_t)(k0 + kk) * DIM + n0 + c4];
        t[c4 + 0][kk] = (_Float16)v.x; t[c4 + 1][kk] = (_Float16)v.y;
        t[c4 + 2][kk] = (_Float16)v.z; t[c4 + 3][kk] = (_Float16)v.w;
    }
    __syncthreads();
    const int nr = tid >> 2, ks = (tid & 3) * 16;
#pragma unroll
    for (int s = 0; s < 4; s++)
        *(ushort4*)&O[(size_t)(n0 + nr) * DIM + k0 + ks + s * 4] =
            *(ushort4*)&t[nr][ks + s * 4];
}

// ---------------- fp16 MFMA GEMM with fused RoPE epilogue ----------------
// QKV=true: q,k written [head][s][hd] with RoPE applied; v written TRANSPOSED [head][hd][s].
template<bool QKV>
__global__ __launch_bounds__(256)
void gemm_f16(const _Float16* __restrict__ X,
              const _Float16* __restrict__ W0t, const _Float16* __restrict__ W1t,
              const _Float16* __restrict__ W2t,
              const float* __restrict__ B0, const float* __restrict__ B1,
              const float* __restrict__ B2,
              const float* __restrict__ fc, const float* __restrict__ fs,
              void* __restrict__ outv)
{
    __shared__ __align__(16) _Float16 As[128][64];   // 16 KB
    __shared__ __align__(16) _Float16 Bs[128][64];   // 16 KB

    const int tid = threadIdx.x;
    const int w = tid >> 6, lane = tid & 63;
    const int ln = lane & 15, quad = lane >> 4;
    const int bz = blockIdx.z;
    const _Float16* Wt = W0t; const float* bias = B0;
    if (QKV) { if (bz == 1) { Wt = W1t; bias = B1; } else if (bz == 2) { Wt = W2t; bias = B2; } }
    const int m0 = blockIdx.y * 128, n0 = blockIdx.x * 128;
    const int wm = w >> 1, wn = w & 1;
    const int row8 = lane >> 3, cch = lane & 7;
    const int gch = cch ^ row8;          // swizzled source chunk index

    f32x4 acc[4][4];
#pragma unroll
    for (int i = 0; i < 4; i++)
#pragma unroll
        for (int j = 0; j < 4; j++) acc[i][j] = (f32x4){0.f, 0.f, 0.f, 0.f};

    for (int k0 = 0; k0 < DIM; k0 += 64) {
        __syncthreads();
#pragma unroll
        for (int j = 0; j < 4; j++) {
            const int r = w * 32 + j * 8;
            gload16(X  + (size_t)(m0 + r + row8) * DIM + k0 + gch * 8, &As[r][0]);
            gload16(Wt + (size_t)(n0 + r + row8) * DIM + k0 + gch * 8, &Bs[r][0]);
        }
        __syncthreads();

        half8 a[4][2], b[4][2];
#pragma unroll
        for (int mt = 0; mt < 4; mt++) {
            int m = wm * 64 + mt * 16 + ln;
#pragma unroll
            for (int ks = 0; ks < 2; ks++) {
                int s = (ks * 4 + quad) ^ (ln & 7);
                a[mt][ks] = *(const half8*)&As[m][s * 8];
            }
        }
#pragma unroll
        for (int nt = 0; nt < 4; nt++) {
            int n = wn * 64 + nt * 16 + ln;
#pragma unroll
            for (int ks = 0; ks < 2; ks++) {
                int s = (ks * 4 + quad) ^ (ln & 7);
                b[nt][ks] = *(const half8*)&Bs[n][s * 8];
            }
        }
#pragma unroll
        for (int ks = 0; ks < 2; ks++)
#pragma unroll
            for (int mt = 0; mt < 4; mt++)
#pragma unroll
                for (int nt = 0; nt < 4; nt++)
                    acc[mt][nt] = __builtin_amdgcn_mfma_f32_16x16x32_f16(
                        a[mt][ks], b[nt][ks], acc[mt][nt], 0, 0, 0);
    }

    // epilogue: C/D 16x16 layout col=ln, row=quad*4+reg
#pragma unroll
    for (int nt = 0; nt < 4; nt++) {
        int col = n0 + wn * 64 + nt * 16 + ln;
        float bv = bias[col];
        int head = col / HDIM, hd = col % HDIM;
        int jc = hd >> 1;                   // pair index; parity of hd == parity of ln
        bool isreal = (ln & 1) == 0;
#pragma unroll
        for (int mt = 0; mt < 4; mt++) {
            int row0 = m0 + wm * 64 + mt * 16 + quad * 4;
            if (QKV && bz == 2) {
                // V^T [head][hd][s]: 4 consecutive s values -> packed 8B store
                half4v p;
#pragma unroll
                for (int r = 0; r < 4; r++) p[r] = (_Float16)(acc[mt][nt][r] + bv);
                *(half4v*)&((_Float16*)outv)[(((size_t)2 * NHEADS + head) * HDIM + hd) * S_LEN + row0] = p;
            } else if (QKV) {
                // q/k with fused RoPE: pair partner lives in lane^1
                float v[4], vp[4];
#pragma unroll
                for (int r = 0; r < 4; r++) v[r] = acc[mt][nt][r] + bv;
#pragma unroll
                for (int r = 0; r < 4; r++) vp[r] = __shfl_xor(v[r], 1);
#pragma unroll
                for (int r = 0; r < 4; r++) {
                    int srow = row0 + r;
                    int pos = (jc < 32) ? (srow >> 6) : (srow & 63);
                    float c  = fc[pos * NPAIR + jc];
                    float sn = fs[pos * NPAIR + jc];
                    float xr = isreal ? v[r] : vp[r];
                    float xi = isreal ? vp[r] : v[r];
                    float rot = isreal ? (xr * c - xi * sn) : (xr * sn + xi * c);
                    float outval = (jc < 16) ? v[r] : rot;
                    ((_Float16*)outv)[(((size_t)bz * NHEADS + head) * S_LEN + srow) * HDIM + hd]
                        = (_Float16)outval;
                }
            } else {
#pragma unroll
                for (int r = 0; r < 4; r++)
                    ((float*)outv)[(size_t)(row0 + r) * DIM + col] = acc[mt][nt][r] + bv;
            }
        }
    }
}

// ---------------- MFMA fp16 flash attention, S^T formulation, reg-prefetch dbuf ----------------
// __launch_bounds__(256,4): min 4 waves/EU -> VGPR cap 128, room for the 24
// prefetch VGPRs that live across the compute phase (R6 spilled them: 787 MB
// scratch writes at VGPR cap 72).
__global__ __launch_bounds__(256, 4)
void attn_mfma_kernel(const _Float16* __restrict__ qh, const _Float16* __restrict__ kh,
                      const _Float16* __restrict__ vtg, _Float16* __restrict__ aoh)
{
    __shared__ __align__(16) _Float16 Ks[64][100];    // 12.5 KB
    __shared__ __align__(16) _Float16 Vt[96][68];     // 12.75 KB
    __shared__ __align__(16) _Float16 Pl[4][16][72];  // 9 KB, wave-private

    const int tid  = threadIdx.x;
    const int wid  = tid >> 6;
    const int lane = tid & 63;
    const int ln   = lane & 15;
    const int quad = lane >> 4;
    const int h    = blockIdx.y;
    const int q0   = blockIdx.x * 64;
    const float scale_ = 0.10206207261596577f;  // 1/sqrt(96)

    // Q fragments (B-operand: lane(ln,quad) holds Q[qrow=ln][d=kb*32+quad*8+j])
    half8 aq[3];
    {
        const _Float16* qrow = qh + (((size_t)h * S_LEN) + q0 + wid * 16 + ln) * HDIM;
#pragma unroll
        for (int kb3 = 0; kb3 < 3; kb3++) {
            half8 a = *(const half8*)&qrow[kb3 * 32 + quad * 8];
            half8 v;
#pragma unroll
            for (int i = 0; i < 8; i++) v[i] = (_Float16)((float)a[i] * scale_);
            aq[kb3] = v;
        }
    }

    f32x4 o[6];  // O^T: o[dn][r] = O^T[dn*16+quad*4+r][qrow=ln]
#pragma unroll
    for (int dn = 0; dn < 6; dn++) o[dn] = (f32x4){0.f, 0.f, 0.f, 0.f};
    float m_ = -INFINITY, l_ = 0.f;   // per-lane (qrow = ln)

    const _Float16* kbase = kh + ((size_t)h * S_LEN) * HDIM;
    const _Float16* vbase = vtg + ((size_t)h * HDIM) * S_LEN;

    // staging index constants (3 uint4 chunks per thread for each of K, V^T)
    const int krow = tid >> 2, kc8 = (tid & 3) * 3;   // K: 64 rows x 12 chunks

    // prefetch tile 0
    uint4 kr[3], vr[3];
#pragma unroll
    for (int u = 0; u < 3; u++)
        kr[u] = *(const uint4*)&kbase[(size_t)krow * HDIM + (kc8 + u) * 8];
#pragma unroll
    for (int u = 0; u < 3; u++) {
        int i = tid + u * 256, d = i >> 3, c = i & 7;
        vr[u] = *(const uint4*)&vbase[(size_t)d * S_LEN + c * 8];
    }

    for (int kt = 0; kt < S_LEN / 64; ++kt) {
        __syncthreads();   // previous tile's LDS reads complete
        // commit prefetched tile to LDS
#pragma unroll
        for (int u = 0; u < 3; u++)
            *(uint4*)&Ks[krow][(kc8 + u) * 8] = kr[u];
#pragma unroll
        for (int u = 0; u < 3; u++) {
            int i = tid + u * 256, d = i >> 3, c = i & 7;
            *(uint4*)&Vt[d][c * 8] = vr[u];
        }
        __syncthreads();

        // issue next tile's global loads (latency hidden behind compute below)
        if (kt + 1 < S_LEN / 64) {
            const int j1 = (kt + 1) * 64;
#pragma unroll
            for (int u = 0; u < 3; u++)
                kr[u] = *(const uint4*)&kbase[(size_t)(j1 + krow) * HDIM + (kc8 + u) * 8];
#pragma unroll
            for (int u = 0; u < 3; u++) {
                int i = tid + u * 256, d = i >> 3, c = i & 7;
                vr[u] = *(const uint4*)&vbase[(size_t)d * S_LEN + j1 + c * 8];
            }
        }

        // S^T = K * Q^T : s[nb][r] = S^T[key=nb*16+quad*4+r][qrow=ln]
        f32x4 s[4];
#pragma unroll
        for (int nb = 0; nb < 4; nb++) {
            f32x4 acc = (f32x4){0.f, 0.f, 0.f, 0.f};
#pragma unroll
            for (int kb3 = 0; kb3 < 3; kb3++) {
                half8 ak = *(const half8*)&Ks[nb * 16 + ln][kb3 * 32 + quad * 8];
                acc = __builtin_amdgcn_mfma_f32_16x16x32_f16(ak, aq[kb3], acc, 0, 0, 0);
            }
            s[nb] = acc;
        }

        // per-lane online softmax over 16 regs, reduce across quads (2 shfl each)
        float mx = s[0][0];
#pragma unroll
        for (int nb = 0; nb < 4; nb++)
#pragma unroll
            for (int r = 0; r < 4; r++) mx = fmaxf(mx, s[nb][r]);
        mx = fmaxf(mx, __shfl_xor(mx, 16));
        mx = fmaxf(mx, __shfl_xor(mx, 32));
        float mn = fmaxf(m_, mx);
        float al = __expf(m_ - mn);
        m_ = mn;
        float rs = 0.f;
#pragma unroll
        for (int nb = 0; nb < 4; nb++)
#pragma unroll
            for (int r = 0; r < 4; r++) {
                float p = __expf(s[nb][r] - mn);
                s[nb][r] = p;
                rs += p;
            }
        rs += __shfl_xor(rs, 16);
        rs += __shfl_xor(rs, 32);
        l_ = l_ * al + rs;

        // P -> wave-private LDS [qrow][key], values already in the right lane
#pragma unroll
        for (int nb = 0; nb < 4; nb++) {
            uint2 u;
            u.x = packh2(s[nb][0], s[nb][1]);
            u.y = packh2(s[nb][2], s[nb][3]);
            *(uint2*)&Pl[wid][ln][nb * 16 + quad * 4] = u;
        }

        // rescale O^T (al is per-lane)
#pragma unroll
        for (int dn = 0; dn < 6; dn++)
#pragma unroll
            for (int r = 0; r < 4; r++) o[dn][r] *= al;

        // O^T += V^T * P
        half8 ap[2];
#pragma unroll
        for (int c = 0; c < 2; c++)
            ap[c] = *(const half8*)&Pl[wid][ln][c * 32 + quad * 8];
#pragma unroll
        for (int dn = 0; dn < 6; dn++) {
#pragma unroll
            for (int c = 0; c < 2; c++) {
                half8 av = *(const half8*)&Vt[dn * 16 + ln][c * 32 + quad * 8];
                o[dn] = __builtin_amdgcn_mfma_f32_16x16x32_f16(av, ap[c], o[dn], 0, 0, 0);
            }
        }
    }

    const float invl = 1.f / l_;
    const size_t rowbase = (size_t)(q0 + wid * 16 + ln) * DIM + h * HDIM;
#pragma unroll
    for (int dn = 0; dn < 6; dn++) {
        half4v p;
#pragma unroll
        for (int r = 0; r < 4; r++) p[r] = (_Float16)(o[dn][r] * invl);
        *(half4v*)&aoh[rowbase + dn * 16 + quad * 4] = p;
    }
}

extern "C" void kernel_launch(void* const* d_in, const int* in_sizes, int n_in,
                              void* d_out, int out_size, void* d_ws, size_t ws_size,
                              hipStream_t stream) {
    const float* x  = (const float*)d_in[0];
    const float* wq = (const float*)d_in[1];
    const float* bq = (const float*)d_in[2];
    const float* wk = (const float*)d_in[3];
    const float* bk = (const float*)d_in[4];
    const float* wv = (const float*)d_in[5];
    const float* bv = (const float*)d_in[6];
    const float* wo = (const float*)d_in[7];
    const float* bo = (const float*)d_in[8];
    const float* fc = (const float*)d_in[9];
    const float* fs = (const float*)d_in[10];
    float* out = (float*)d_out;

    const size_t per  = (size_t)NHEADS * S_LEN * HDIM;   // 4,718,592
    const size_t dim2 = (size_t)DIM * DIM;               // 2,359,296
    _Float16* hws  = (_Float16*)d_ws;
    _Float16* qkvh = hws;                 // q,k fp16 [head][s][hd] (roped); v fp16 [head][hd][s]
    _Float16* qh   = qkvh;
    _Float16* kh   = qkvh + per;
    _Float16* vth  = qkvh + 2 * per;
    _Float16* xh   = hws + 3 * per;       // x fp16; later reused as ao fp16
    _Float16* wth  = hws + 4 * per;       // 4 transposed weights fp16

    convert_f32_f16<<<(int)((S_LEN * DIM / 4 + 255) / 256), 256, 0, stream>>>(
        x, xh, S_LEN * DIM / 4);
    transpose_w<<<dim3(DIM / 64, DIM / 64, 4), 256, 0, stream>>>(wq, wk, wv, wo, wth);

    // fused QKV projection + RoPE -> fp16
    gemm_f16<true><<<dim3(DIM / 128, S_LEN / 128, 3), 256, 0, stream>>>(
        xh, wth, wth + dim2, wth + 2 * dim2, bq, bk, bv, fc, fs, qkvh);
    attn_mfma_kernel<<<dim3(S_LEN / 64, NHEADS), 256, 0, stream>>>(qh, kh, vth, xh);
    gemm_f16<false><<<dim3(DIM / 128, S_LEN / 128, 1), 256, 0, stream>>>(
        xh, wth + 3 * dim2, nullptr, nullptr, bo, nullptr, nullptr, fc, fs, out);
}

// Round 8
// 336.306 us; speedup vs baseline: 1.4150x; 1.4150x over previous
//
#include <hip/hip_runtime.h>
#include <math.h>

#define S_LEN 3072
#define DIM 1536
#define NHEADS 16
#define HDIM 96
#define NPAIR 48

typedef __attribute__((ext_vector_type(8))) _Float16 half8;
typedef __attribute__((ext_vector_type(4))) _Float16 half4v;
typedef __attribute__((ext_vector_type(2))) _Float16 half2v;
typedef __attribute__((ext_vector_type(4))) float f32x4;

__device__ inline void gload16(const void* g, void* l) {
    __builtin_amdgcn_global_load_lds(
        (const __attribute__((address_space(1))) void*)g,
        (__attribute__((address_space(3))) void*)l, 16, 0, 0);
}

__device__ inline unsigned int packh2(float a, float b) {
    _Float16 ha = (_Float16)a, hb = (_Float16)b;
    unsigned short ua = *(unsigned short*)&ha;
    unsigned short ub = *(unsigned short*)&hb;
    return (unsigned int)ua | ((unsigned int)ub << 16);
}

// ---------------- prep: fp32 -> fp16 elementwise ----------------
__global__ __launch_bounds__(256)
void convert_f32_f16(const float* __restrict__ src, _Float16* __restrict__ dst, int n4)
{
    int i = blockIdx.x * 256 + threadIdx.x;
    if (i < n4) {
        float4 v = *(const float4*)&src[(size_t)i * 4];
        half4v h = { (_Float16)v.x, (_Float16)v.y, (_Float16)v.z, (_Float16)v.w };
        *(half4v*)&dst[(size_t)i * 4] = h;
    }
}

// ---------------- prep: W[k][n] fp32 -> Wt[n][k] fp16 (64x64 LDS tiles) ----------------
__global__ __launch_bounds__(256)
void transpose_w(const float* __restrict__ w0, const float* __restrict__ w1,
                 const float* __restrict__ w2, const float* __restrict__ w3,
                 _Float16* __restrict__ wt)
{
    __shared__ _Float16 t[64][68];
    const int z = blockIdx.z;
    const float* W = (z == 0) ? w0 : (z == 1) ? w1 : (z == 2) ? w2 : w3;
    _Float16* O = wt + (size_t)z * DIM * DIM;
    const int k0 = blockIdx.y * 64, n0 = blockIdx.x * 64;
    const int tid = threadIdx.x;
    const int r = tid >> 4, c4 = (tid & 15) * 4;
#pragma unroll
    for (int g = 0; g < 4; g++) {
        int kk = r + g * 16;
        float4 v = *(const float4*)&W[(size_t)(k0 + kk) * DIM + n0 + c4];
        t[c4 + 0][kk] = (_Float16)v.x; t[c4 + 1][kk] = (_Float16)v.y;
        t[c4 + 2][kk] = (_Float16)v.z; t[c4 + 3][kk] = (_Float16)v.w;
    }
    __syncthreads();
    const int nr = tid >> 2, ks = (tid & 3) * 16;
#pragma unroll
    for (int s = 0; s < 4; s++)
        *(ushort4*)&O[(size_t)(n0 + nr) * DIM + k0 + ks + s * 4] =
            *(ushort4*)&t[nr][ks + s * 4];
}

// ---------------- fp16 MFMA GEMM with fused RoPE epilogue ----------------
// QKV=true: q,k written [head][s][hd] with RoPE applied; v written TRANSPOSED [head][hd][s].
template<bool QKV>
__global__ __launch_bounds__(256)
void gemm_f16(const _Float16* __restrict__ X,
              const _Float16* __restrict__ W0t, const _Float16* __restrict__ W1t,
              const _Float16* __restrict__ W2t,
              const float* __restrict__ B0, const float* __restrict__ B1,
              const float* __restrict__ B2,
              const float* __restrict__ fc, const float* __restrict__ fs,
              void* __restrict__ outv)
{
    __shared__ __align__(16) _Float16 As[128][64];   // 16 KB
    __shared__ __align__(16) _Float16 Bs[128][64];   // 16 KB

    const int tid = threadIdx.x;
    const int w = tid >> 6, lane = tid & 63;
    const int ln = lane & 15, quad = lane >> 4;
    const int bz = blockIdx.z;
    const _Float16* Wt = W0t; const float* bias = B0;
    if (QKV) { if (bz == 1) { Wt = W1t; bias = B1; } else if (bz == 2) { Wt = W2t; bias = B2; } }
    const int m0 = blockIdx.y * 128, n0 = blockIdx.x * 128;
    const int wm = w >> 1, wn = w & 1;
    const int row8 = lane >> 3, cch = lane & 7;
    const int gch = cch ^ row8;          // swizzled source chunk index

    f32x4 acc[4][4];
#pragma unroll
    for (int i = 0; i < 4; i++)
#pragma unroll
        for (int j = 0; j < 4; j++) acc[i][j] = (f32x4){0.f, 0.f, 0.f, 0.f};

    for (int k0 = 0; k0 < DIM; k0 += 64) {
        __syncthreads();
#pragma unroll
        for (int j = 0; j < 4; j++) {
            const int r = w * 32 + j * 8;
            gload16(X  + (size_t)(m0 + r + row8) * DIM + k0 + gch * 8, &As[r][0]);
            gload16(Wt + (size_t)(n0 + r + row8) * DIM + k0 + gch * 8, &Bs[r][0]);
        }
        __syncthreads();

        half8 a[4][2], b[4][2];
#pragma unroll
        for (int mt = 0; mt < 4; mt++) {
            int m = wm * 64 + mt * 16 + ln;
#pragma unroll
            for (int ks = 0; ks < 2; ks++) {
                int s = (ks * 4 + quad) ^ (ln & 7);
                a[mt][ks] = *(const half8*)&As[m][s * 8];
            }
        }
#pragma unroll
        for (int nt = 0; nt < 4; nt++) {
            int n = wn * 64 + nt * 16 + ln;
#pragma unroll
            for (int ks = 0; ks < 2; ks++) {
                int s = (ks * 4 + quad) ^ (ln & 7);
                b[nt][ks] = *(const half8*)&Bs[n][s * 8];
            }
        }
#pragma unroll
        for (int ks = 0; ks < 2; ks++)
#pragma unroll
            for (int mt = 0; mt < 4; mt++)
#pragma unroll
                for (int nt = 0; nt < 4; nt++)
                    acc[mt][nt] = __builtin_amdgcn_mfma_f32_16x16x32_f16(
                        a[mt][ks], b[nt][ks], acc[mt][nt], 0, 0, 0);
    }

    // epilogue: C/D 16x16 layout col=ln, row=quad*4+reg
#pragma unroll
    for (int nt = 0; nt < 4; nt++) {
        int col = n0 + wn * 64 + nt * 16 + ln;
        float bv = bias[col];
        int head = col / HDIM, hd = col % HDIM;
        int jc = hd >> 1;                   // pair index; parity of hd == parity of ln
        bool isreal = (ln & 1) == 0;
#pragma unroll
        for (int mt = 0; mt < 4; mt++) {
            int row0 = m0 + wm * 64 + mt * 16 + quad * 4;
            if (QKV && bz == 2) {
                // V^T [head][hd][s]: 4 consecutive s values -> packed 8B store
                half4v p;
#pragma unroll
                for (int r = 0; r < 4; r++) p[r] = (_Float16)(acc[mt][nt][r] + bv);
                *(half4v*)&((_Float16*)outv)[(((size_t)2 * NHEADS + head) * HDIM + hd) * S_LEN + row0] = p;
            } else if (QKV) {
                // q/k with fused RoPE: pair partner lives in lane^1
                float v[4], vp[4];
#pragma unroll
                for (int r = 0; r < 4; r++) v[r] = acc[mt][nt][r] + bv;
#pragma unroll
                for (int r = 0; r < 4; r++) vp[r] = __shfl_xor(v[r], 1);
#pragma unroll
                for (int r = 0; r < 4; r++) {
                    int srow = row0 + r;
                    int pos = (jc < 32) ? (srow >> 6) : (srow & 63);
                    float c  = fc[pos * NPAIR + jc];
                    float sn = fs[pos * NPAIR + jc];
                    float xr = isreal ? v[r] : vp[r];
                    float xi = isreal ? vp[r] : v[r];
                    float rot = isreal ? (xr * c - xi * sn) : (xr * sn + xi * c);
                    float outval = (jc < 16) ? v[r] : rot;
                    ((_Float16*)outv)[(((size_t)bz * NHEADS + head) * S_LEN + srow) * HDIM + hd]
                        = (_Float16)outval;
                }
            } else {
#pragma unroll
                for (int r = 0; r < 4; r++)
                    ((float*)outv)[(size_t)(row0 + r) * DIM + col] = acc[mt][nt][r] + bv;
            }
        }
    }
}

// ---------------- MFMA fp16 flash attention ----------------
// 128 threads / 2 waves; each wave owns 32 q-rows (2 q-blocks) -> every K/V
// LDS fragment read is reused across 2 q-blocks (R5 was LDS-throughput-bound).
// Prefetch in NAMED uint4 scalars (R6/R7: uint4 ARRAYS were sunk to scratch,
// 787 MB WRITE_SIZE). Vt: pow2 stride 64 + XOR chunk swizzle (bank-balanced).
__global__ __launch_bounds__(128, 2)
void attn_mfma_kernel(const _Float16* __restrict__ qh, const _Float16* __restrict__ kh,
                      const _Float16* __restrict__ vtg, _Float16* __restrict__ aoh)
{
    __shared__ __align__(16) _Float16 Ks[64][104];    // 13.3 KB, stride 208B (balanced)
    __shared__ __align__(16) _Float16 Vt[96][64];     // 12 KB, XOR-swizzled chunks
    __shared__ __align__(16) _Float16 Pl[4][16][72];  // 9.2 KB, wave-private slots

    const int tid  = threadIdx.x;      // 0..127
    const int wid  = tid >> 6;         // 0..1
    const int lane = tid & 63;
    const int ln   = lane & 15;
    const int quad = lane >> 4;
    const int h    = blockIdx.y;
    const int q0   = blockIdx.x * 64;
    const float scale_ = 0.10206207261596577f;  // 1/sqrt(96)
    const int NT = S_LEN / 64;

    // Q fragments for 2 q-blocks (B-operand: col=ln=qrow, k=quad*8+j)
    half8 aq[2][3];
#pragma unroll
    for (int qs = 0; qs < 2; qs++) {
        const _Float16* qrow = qh + (((size_t)h * S_LEN) + q0 + (wid * 2 + qs) * 16 + ln) * HDIM;
#pragma unroll
        for (int kb3 = 0; kb3 < 3; kb3++) {
            half8 a = *(const half8*)&qrow[kb3 * 32 + quad * 8];
            half8 v;
#pragma unroll
            for (int i = 0; i < 8; i++) v[i] = (_Float16)((float)a[i] * scale_);
            aq[qs][kb3] = v;
        }
    }

    f32x4 o[2][6];
#pragma unroll
    for (int qs = 0; qs < 2; qs++)
#pragma unroll
        for (int dn = 0; dn < 6; dn++) o[qs][dn] = (f32x4){0.f, 0.f, 0.f, 0.f};
    float m_[2] = {-INFINITY, -INFINITY}, l_[2] = {0.f, 0.f};

    const _Float16* kbase = kh + ((size_t)h * S_LEN) * HDIM;
    const _Float16* vbase = vtg + ((size_t)h * HDIM) * S_LEN;

    // K staging: thread t -> row t>>1, 6 contiguous 16B chunks at (t&1)*6
    const int krow = tid >> 1, kc0 = (tid & 1) * 6;
    const _Float16* ksrc0 = kbase + (size_t)krow * HDIM + kc0 * 8;
    _Float16* kdst = &Ks[krow][kc0 * 8];
    // V staging: thread t -> d rows (t>>3)+16u, chunk c=t&7; XOR slot = c^(d&7)
    const int vd0 = tid >> 3, vc = tid & 7;
    const _Float16* vsrc0 = vbase + (size_t)vd0 * S_LEN + vc * 8;
    _Float16* vdst = &Vt[vd0][(vc ^ (vd0 & 7)) * 8];

    // prefetch tile 0 (named scalars -> guaranteed SSA/registers)
    uint4 kp0, kp1, kp2, kp3, kp4, kp5, vp0, vp1, vp2, vp3, vp4, vp5;
    kp0 = *(const uint4*)(ksrc0 + 0 * 8);  kp1 = *(const uint4*)(ksrc0 + 1 * 8);
    kp2 = *(const uint4*)(ksrc0 + 2 * 8);  kp3 = *(const uint4*)(ksrc0 + 3 * 8);
    kp4 = *(const uint4*)(ksrc0 + 4 * 8);  kp5 = *(const uint4*)(ksrc0 + 5 * 8);
    vp0 = *(const uint4*)(vsrc0 + 0 * 16 * S_LEN);
    vp1 = *(const uint4*)(vsrc0 + 1 * 16 * S_LEN);
    vp2 = *(const uint4*)(vsrc0 + 2 * 16 * S_LEN);
    vp3 = *(const uint4*)(vsrc0 + 3 * 16 * S_LEN);
    vp4 = *(const uint4*)(vsrc0 + 4 * 16 * S_LEN);
    vp5 = *(const uint4*)(vsrc0 + 5 * 16 * S_LEN);

    for (int kt = 0; kt < NT; ++kt) {
        __syncthreads();   // previous tile's LDS reads complete
        // commit prefetched tile to LDS
        *(uint4*)(kdst + 0 * 8) = kp0;  *(uint4*)(kdst + 1 * 8) = kp1;
        *(uint4*)(kdst + 2 * 8) = kp2;  *(uint4*)(kdst + 3 * 8) = kp3;
        *(uint4*)(kdst + 4 * 8) = kp4;  *(uint4*)(kdst + 5 * 8) = kp5;
        *(uint4*)(vdst + 0 * 16 * 64) = vp0;  *(uint4*)(vdst + 1 * 16 * 64) = vp1;
        *(uint4*)(vdst + 2 * 16 * 64) = vp2;  *(uint4*)(vdst + 3 * 16 * 64) = vp3;
        *(uint4*)(vdst + 4 * 16 * 64) = vp4;  *(uint4*)(vdst + 5 * 16 * 64) = vp5;
        __syncthreads();

        // issue next tile's global loads (consumed at next tile's ds_write)
        if (kt + 1 < NT) {
            const _Float16* ks2 = ksrc0 + (size_t)(kt + 1) * 64 * HDIM;
            const _Float16* vs2 = vsrc0 + (kt + 1) * 64;
            kp0 = *(const uint4*)(ks2 + 0 * 8);  kp1 = *(const uint4*)(ks2 + 1 * 8);
            kp2 = *(const uint4*)(ks2 + 2 * 8);  kp3 = *(const uint4*)(ks2 + 3 * 8);
            kp4 = *(const uint4*)(ks2 + 4 * 8);  kp5 = *(const uint4*)(ks2 + 5 * 8);
            vp0 = *(const uint4*)(vs2 + 0 * 16 * S_LEN);
            vp1 = *(const uint4*)(vs2 + 1 * 16 * S_LEN);
            vp2 = *(const uint4*)(vs2 + 2 * 16 * S_LEN);
            vp3 = *(const uint4*)(vs2 + 3 * 16 * S_LEN);
            vp4 = *(const uint4*)(vs2 + 4 * 16 * S_LEN);
            vp5 = *(const uint4*)(vs2 + 5 * 16 * S_LEN);
        }

        // S^T = K * Q^T; K-frags read ONCE, used for both q-blocks
        f32x4 s[2][4];
#pragma unroll
        for (int nb = 0; nb < 4; nb++) {
            half8 ak0 = *(const half8*)&Ks[nb * 16 + ln][0 * 32 + quad * 8];
            half8 ak1 = *(const half8*)&Ks[nb * 16 + ln][1 * 32 + quad * 8];
            half8 ak2 = *(const half8*)&Ks[nb * 16 + ln][2 * 32 + quad * 8];
#pragma unroll
            for (int qs = 0; qs < 2; qs++) {
                f32x4 acc = (f32x4){0.f, 0.f, 0.f, 0.f};
                acc = __builtin_amdgcn_mfma_f32_16x16x32_f16(ak0, aq[qs][0], acc, 0, 0, 0);
                acc = __builtin_amdgcn_mfma_f32_16x16x32_f16(ak1, aq[qs][1], acc, 0, 0, 0);
                acc = __builtin_amdgcn_mfma_f32_16x16x32_f16(ak2, aq[qs][2], acc, 0, 0, 0);
                s[qs][nb] = acc;
            }
        }

        // per-lane online softmax (qrow = ln), cross-quad reduce: 2 shfl each
        float al[2];
#pragma unroll
        for (int qs = 0; qs < 2; qs++) {
            float mx = s[qs][0][0];
#pragma unroll
            for (int nb = 0; nb < 4; nb++)
#pragma unroll
                for (int r = 0; r < 4; r++) mx = fmaxf(mx, s[qs][nb][r]);
            mx = fmaxf(mx, __shfl_xor(mx, 16));
            mx = fmaxf(mx, __shfl_xor(mx, 32));
            float mn = fmaxf(m_[qs], mx);
            al[qs] = __expf(m_[qs] - mn);
            m_[qs] = mn;
            float rs = 0.f;
#pragma unroll
            for (int nb = 0; nb < 4; nb++)
#pragma unroll
                for (int r = 0; r < 4; r++) {
                    float p = __expf(s[qs][nb][r] - mn);
                    s[qs][nb][r] = p;
                    rs += p;
                }
            rs += __shfl_xor(rs, 16);
            rs += __shfl_xor(rs, 32);
            l_[qs] = l_[qs] * al[qs] + rs;

            // P -> wave-private LDS slot (wid*2+qs); no barrier needed (same wave)
#pragma unroll
            for (int nb = 0; nb < 4; nb++) {
                uint2 u;
                u.x = packh2(s[qs][nb][0], s[qs][nb][1]);
                u.y = packh2(s[qs][nb][2], s[qs][nb][3]);
                *(uint2*)&Pl[wid * 2 + qs][ln][nb * 16 + quad * 4] = u;
            }
            // rescale O
#pragma unroll
            for (int dn = 0; dn < 6; dn++)
#pragma unroll
                for (int r = 0; r < 4; r++) o[qs][dn][r] *= al[qs];
        }

        // PV: V-frags read ONCE, used for both q-blocks
        half8 ap[2][2];
#pragma unroll
        for (int qs = 0; qs < 2; qs++)
#pragma unroll
            for (int c = 0; c < 2; c++)
                ap[qs][c] = *(const half8*)&Pl[wid * 2 + qs][ln][c * 32 + quad * 8];
#pragma unroll
        for (int c = 0; c < 2; c++) {
#pragma unroll
            for (int dn = 0; dn < 6; dn++) {
                int row = dn * 16 + ln;
                int slot = (c * 4 + quad) ^ (ln & 7);
                half8 av = *(const half8*)&Vt[row][slot * 8];
                o[0][dn] = __builtin_amdgcn_mfma_f32_16x16x32_f16(av, ap[0][c], o[0][dn], 0, 0, 0);
                o[1][dn] = __builtin_amdgcn_mfma_f32_16x16x32_f16(av, ap[1][c], o[1][dn], 0, 0, 0);
            }
        }
    }

#pragma unroll
    for (int qs = 0; qs < 2; qs++) {
        const float invl = 1.f / l_[qs];
        const size_t rowbase = (size_t)(q0 + (wid * 2 + qs) * 16 + ln) * DIM + h * HDIM;
#pragma unroll
        for (int dn = 0; dn < 6; dn++) {
            half4v p;
#pragma unroll
            for (int r = 0; r < 4; r++) p[r] = (_Float16)(o[qs][dn][r] * invl);
            *(half4v*)&aoh[rowbase + dn * 16 + quad * 4] = p;
        }
    }
}

extern "C" void kernel_launch(void* const* d_in, const int* in_sizes, int n_in,
                              void* d_out, int out_size, void* d_ws, size_t ws_size,
                              hipStream_t stream) {
    const float* x  = (const float*)d_in[0];
    const float* wq = (const float*)d_in[1];
    const float* bq = (const float*)d_in[2];
    const float* wk = (const float*)d_in[3];
    const float* bk = (const float*)d_in[4];
    const float* wv = (const float*)d_in[5];
    const float* bv = (const float*)d_in[6];
    const float* wo = (const float*)d_in[7];
    const float* bo = (const float*)d_in[8];
    const float* fc = (const float*)d_in[9];
    const float* fs = (const float*)d_in[10];
    float* out = (float*)d_out;

    const size_t per  = (size_t)NHEADS * S_LEN * HDIM;   // 4,718,592
    const size_t dim2 = (size_t)DIM * DIM;               // 2,359,296
    _Float16* hws  = (_Float16*)d_ws;
    _Float16* qkvh = hws;                 // q,k fp16 [head][s][hd] (roped); v fp16 [head][hd][s]
    _Float16* qh   = qkvh;
    _Float16* kh   = qkvh + per;
    _Float16* vth  = qkvh + 2 * per;
    _Float16* xh   = hws + 3 * per;       // x fp16; later reused as ao fp16
    _Float16* wth  = hws + 4 * per;       // 4 transposed weights fp16

    convert_f32_f16<<<(int)((S_LEN * DIM / 4 + 255) / 256), 256, 0, stream>>>(
        x, xh, S_LEN * DIM / 4);
    transpose_w<<<dim3(DIM / 64, DIM / 64, 4), 256, 0, stream>>>(wq, wk, wv, wo, wth);

    // fused QKV projection + RoPE -> fp16
    gemm_f16<true><<<dim3(DIM / 128, S_LEN / 128, 3), 256, 0, stream>>>(
        xh, wth, wth + dim2, wth + 2 * dim2, bq, bk, bv, fc, fs, qkvh);
    attn_mfma_kernel<<<dim3(S_LEN / 64, NHEADS), 128, 0, stream>>>(qh, kh, vth, xh);
    gemm_f16<false><<<dim3(DIM / 128, S_LEN / 128, 1), 256, 0, stream>>>(
        xh, wth + 3 * dim2, nullptr, nullptr, bo, nullptr, nullptr, fc, fs, out);
}